// Round 18
// baseline (130.544 us; speedup 1.0000x reference)
//
#include <hip/hip_runtime.h>
#include <math.h>

typedef __bf16 bf16x8 __attribute__((ext_vector_type(8)));
typedef float f32x4 __attribute__((ext_vector_type(4)));

namespace {
constexpr int DIMC = 1024, NH = 16, HD = 64, SEQ = 2048;
constexpr float SCL2 = 0.1803368801f;  // 1/(tau*sqrt(64)) * log2(e), folded into Q
}

__device__ __forceinline__ unsigned short f2b(float f) {
  unsigned u = __float_as_uint(f);
  return (unsigned short)((u + 0x7fffu + ((u >> 16) & 1u)) >> 16);
}
__device__ __forceinline__ float b2f(unsigned short s) {
  return __uint_as_float((unsigned)s << 16);
}
__device__ __forceinline__ unsigned cvtpk(float lo, float hi) {
  unsigned r;
  asm("v_cvt_pk_bf16_f32 %0, %1, %2" : "=v"(r) : "v"(lo), "v"(hi));
  return r;
}
__device__ __forceinline__ void gld16(void* l, const void* g) {
  __builtin_amdgcn_global_load_lds(
      (const __attribute__((address_space(1))) void*)g,
      (__attribute__((address_space(3))) void*)l, 16, 0, 0);
}

// single fused fp32->bf16 pass: blocks [0,2048) convert x, [2048,4096) weights
__global__ __launch_bounds__(256)
void cvt_all(const float* __restrict__ x,
             const float* __restrict__ w0, const float* __restrict__ w1,
             const float* __restrict__ w2, const float* __restrict__ w3,
             unsigned short* __restrict__ xb, unsigned short* __restrict__ wb) {
  const int bid = blockIdx.x;
  const float* src;
  unsigned short* dst;
  int i;
  if (bid < 2048) {
    src = x; dst = xb; i = bid * 256 + threadIdx.x;
  } else {
    const int r = (bid - 2048) >> 9, lb = (bid - 2048) & 511;
    src = r == 0 ? w0 : r == 1 ? w1 : r == 2 ? w2 : w3;
    dst = wb + (size_t)r * 1048576;
    i = lb * 256 + threadIdx.x;
  }
  const float4* in4 = (const float4*)src;
  float4 a = in4[2 * i], b = in4[2 * i + 1];
  union { unsigned short u[8]; uint4 v; } r;
  r.u[0] = f2b(a.x); r.u[1] = f2b(a.y); r.u[2] = f2b(a.z); r.u[3] = f2b(a.w);
  r.u[4] = f2b(b.x); r.u[5] = f2b(b.y); r.u[6] = f2b(b.z); r.u[7] = f2b(b.w);
  ((uint4*)dst)[i] = r.v;
}

// ---- m97-structure GEMM tile: BM=BN=128, BK=32, gld16 staging, 16 MFMA/K-step ----
// kswz: K rows written with d ^= ((seq&7)<<3) (attention staging swizzle).
// vtg:  if non-null (V), ALSO write transposed+swizzled [bh][d][s] copy.
template<int MODE>
__device__ __forceinline__
void gemm_tile128(const unsigned short* __restrict__ A, const unsigned short* __restrict__ W,
                  const float* __restrict__ bias, void* __restrict__ Cout,
                  int bm, int bn, float scl, bool kswz,
                  unsigned short* __restrict__ vtg, char* As, char* Bs) {
  const int tid = threadIdx.x, lane = tid & 63, w = tid >> 6;
  const int p = lane & 15, g = lane >> 4;
  const int wr = w >> 1, wc = w & 1;
  const int sr = tid >> 2, sc = (tid & 3) * 8;

  f32x4 acc[4][4];
#pragma unroll
  for (int mf = 0; mf < 4; ++mf)
#pragma unroll
    for (int nf = 0; nf < 4; ++nf)
      acc[mf][nf] = (f32x4){0.f, 0.f, 0.f, 0.f};

  const size_t arow0 = (size_t)(bm + sr) * DIMC + sc;
  const size_t arow1 = (size_t)(bm + 64 + sr) * DIMC + sc;
  const size_t brow0 = (size_t)(bn + sr) * DIMC + sc;
  const size_t brow1 = (size_t)(bn + 64 + sr) * DIMC + sc;

  for (int k0 = 0; k0 < DIMC; k0 += 32) {
    __syncthreads();
    gld16(&As[tid * 16],        &A[arow0 + k0]);
    gld16(&As[4096 + tid * 16], &A[arow1 + k0]);
    gld16(&Bs[tid * 16],        &W[brow0 + k0]);
    gld16(&Bs[4096 + tid * 16], &W[brow1 + k0]);
    __syncthreads();
    bf16x8 af[4], bfr[4];
#pragma unroll
    for (int mf = 0; mf < 4; ++mf)
      af[mf] = *(const bf16x8*)&As[(wr * 64 + mf * 16 + p) * 64 + g * 16];
#pragma unroll
    for (int nf = 0; nf < 4; ++nf)
      bfr[nf] = *(const bf16x8*)&Bs[(wc * 64 + nf * 16 + p) * 64 + g * 16];
#pragma unroll
    for (int mf = 0; mf < 4; ++mf)
#pragma unroll
      for (int nf = 0; nf < 4; ++nf)
        acc[mf][nf] = __builtin_amdgcn_mfma_f32_16x16x32_bf16(af[mf], bfr[nf], acc[mf][nf], 0, 0, 0);
  }

#pragma unroll
  for (int nf = 0; nf < 4; ++nf) {
    const int cg = bn + wc * 64 + nf * 16 + p;
    const float bv = bias[cg & (DIMC - 1)];
#pragma unroll
    for (int mf = 0; mf < 4; ++mf) {
#pragma unroll
      for (int j = 0; j < 4; ++j) {
        const int rg = bm + wr * 64 + mf * 16 + g * 4 + j;
        const float v = (acc[mf][nf][j] + bv) * scl;
        if (MODE == 0) {
          ((float*)Cout)[(size_t)rg * DIMC + cg] = v;
        } else {
          const int bb = rg >> 11, ss = rg & (SEQ - 1);
          const int hh = cg >> 6;
          const int d0 = cg & (HD - 1);
          const unsigned short bv16 = f2b(v);
          int dd = d0;
          if (kswz) dd ^= (ss & 7) << 3;
          ((unsigned short*)Cout)[(((size_t)(bb * NH + hh) * SEQ + ss) * HD) + dd] = bv16;
          if (vtg) {   // transposed+swizzled copy for attention V staging
            vtg[(size_t)(bb * NH + hh) * 131072 + (size_t)d0 * 2048 +
                (ss >> 6) * 64 + ((ss & 63) ^ ((d0 & 7) << 3))] = bv16;
          }
        }
      }
    }
  }
}

// fused Q/K/V projection: grid (32, 8, 3); z selects weight/bias/out.
// Q pre-scaled by SCL2; K row-swizzled; V dual-written (normal + transposed).
__global__ __launch_bounds__(256, 2)
void gemm_qkv(const unsigned short* __restrict__ A, const unsigned short* __restrict__ Wall,
              const float* __restrict__ bq, const float* __restrict__ bk,
              const float* __restrict__ bv, unsigned short* __restrict__ Out,
              unsigned short* __restrict__ Vtg) {
  __shared__ char As[8192];
  __shared__ char Bs[8192];
  const int which = blockIdx.z;
  const unsigned short* W = Wall + (size_t)which * 1048576;
  const float* bias = which == 0 ? bq : which == 1 ? bk : bv;
  unsigned short* Cout = Out + (size_t)which * 4194304;
  const float scl = which == 0 ? SCL2 : 1.0f;
  gemm_tile128<1>(A, W, bias, Cout, blockIdx.x * 128, blockIdx.y * 128, scl,
                  which == 1, which == 2 ? Vtg : nullptr, As, Bs);
}

// ---- gemm_out: 128x64 tile, gld16 staging, 512 blocks = 2/CU ----
__global__ __launch_bounds__(256, 2)
void gemm_out(const unsigned short* __restrict__ A, const unsigned short* __restrict__ W,
              const float* __restrict__ bias, float* __restrict__ Cout) {
  __shared__ char As[8192];  // [128][32] bf16
  __shared__ char Bs[4096];  // [64][32] bf16
  const int tid = threadIdx.x, lane = tid & 63, w = tid >> 6;
  const int p = lane & 15, g = lane >> 4;
  const int wr = w >> 1, wc = w & 1;
  const int bm = blockIdx.x * 128, bn = blockIdx.y * 64;
  const int sr = tid >> 2, sc = (tid & 3) * 8;

  f32x4 acc[4][2];
#pragma unroll
  for (int mf = 0; mf < 4; ++mf)
#pragma unroll
    for (int nf = 0; nf < 2; ++nf)
      acc[mf][nf] = (f32x4){0.f, 0.f, 0.f, 0.f};

  const size_t arow0 = (size_t)(bm + sr) * DIMC + sc;
  const size_t arow1 = (size_t)(bm + 64 + sr) * DIMC + sc;
  const size_t brow  = (size_t)(bn + sr) * DIMC + sc;

  for (int k0 = 0; k0 < DIMC; k0 += 32) {
    __syncthreads();
    gld16(&As[tid * 16],        &A[arow0 + k0]);
    gld16(&As[4096 + tid * 16], &A[arow1 + k0]);
    gld16(&Bs[tid * 16],        &W[brow + k0]);
    __syncthreads();
    bf16x8 af[4], bfr[2];
#pragma unroll
    for (int mf = 0; mf < 4; ++mf)
      af[mf] = *(const bf16x8*)&As[(wr * 64 + mf * 16 + p) * 64 + g * 16];
#pragma unroll
    for (int nf = 0; nf < 2; ++nf)
      bfr[nf] = *(const bf16x8*)&Bs[(wc * 32 + nf * 16 + p) * 64 + g * 16];
#pragma unroll
    for (int mf = 0; mf < 4; ++mf)
#pragma unroll
      for (int nf = 0; nf < 2; ++nf)
        acc[mf][nf] = __builtin_amdgcn_mfma_f32_16x16x32_bf16(af[mf], bfr[nf], acc[mf][nf], 0, 0, 0);
  }

#pragma unroll
  for (int nf = 0; nf < 2; ++nf) {
    const int cg = bn + wc * 32 + nf * 16 + p;
    const float bv = bias[cg];
#pragma unroll
    for (int mf = 0; mf < 4; ++mf) {
#pragma unroll
      for (int j = 0; j < 4; ++j) {
        const int rg = bm + wr * 64 + mf * 16 + g * 4 + j;
        Cout[(size_t)rg * DIMC + cg] = acc[mf][nf][j] + bv;
      }
    }
  }
}

// Fused flash attention: BOTH K and V staged via global_load_lds (V from the
// pre-transposed+swizzled Vtg layout). 8 waves x 16 q-rows, dbuf, 1 barrier/tile.
__global__ __launch_bounds__(512, 4)
void attn_fused(const unsigned short* __restrict__ Q, const unsigned short* __restrict__ K,
                const unsigned short* __restrict__ Vtg, const unsigned short* __restrict__ Vh,
                unsigned short* __restrict__ Y) {
  __shared__ char Kl[2][8192];   // K tile [64 key][64 d] bf16, pre-swizzled rows
  __shared__ char Vt[2][8192];   // V^T [64 d][64 key] bf16, pre-swizzled rows
  __shared__ char Pl[16384];     // per-wave P [16 q][64 key] bf16 (8 x 2KB)
  const int tid = threadIdx.x, lane = tid & 63, w = tid >> 6;
  const int p = lane & 15, g = lane >> 4;
  const int bh = blockIdx.x, b = bh >> 4, h = bh & 15;
  const int q0 = blockIdx.y * 128;
  const int qwv = q0 + w * 16;
  const size_t base = (size_t)bh * SEQ * HD;
  const unsigned short* Qp = Q + base;
  const unsigned short* Vp = Vh + base;

  // Q fragments: q = qwv + p, k(d) = ks*32 + g*8 + j
  bf16x8 qf[2];
#pragma unroll
  for (int ks = 0; ks < 2; ++ks)
    qf[ks] = *(const bf16x8*)&Qp[(size_t)(qwv + p) * HD + ks * 32 + g * 8];

  bf16x8 ones8;
  {
    union { unsigned short u[8]; bf16x8 v; } o;
#pragma unroll
    for (int e = 0; e < 8; ++e) o.u[e] = (p == 0) ? (unsigned short)0x3F80 : (unsigned short)0;
    ones8 = o.v;
  }

  // staging sources (advance per tile): K rows [key][d], V rows [d][key-tile]
  const unsigned short* kSrc = K + base + (size_t)(tid >> 3) * HD + (tid & 7) * 8;
  const unsigned short* vSrc = Vtg + (size_t)bh * 131072 + (size_t)(tid >> 3) * 2048 + (tid & 7) * 8;

  const int swz = (p & 7) << 4;
  int sCol[2], pwCol[4];
#pragma unroll
  for (int ks = 0; ks < 2; ++ks) sCol[ks] = (ks * 64 + g * 16) ^ swz;
#pragma unroll
  for (int nf = 0; nf < 4; ++nf) pwCol[nf] = (nf * 32 + g * 8) ^ swz;

  f32x4 o2[4];   // O^T frags: col q = p, row d = nfd*16 + g*4 + j
  f32x4 ol;      // l: row 0 (g==0,j==0), col q = p
#pragma unroll
  for (int nf = 0; nf < 4; ++nf) o2[nf] = (f32x4){0.f, 0.f, 0.f, 0.f};
  ol = (f32x4){0.f, 0.f, 0.f, 0.f};

  auto gldKV = [&](int par) {
    gld16(&Kl[par][tid * 16], kSrc);
    gld16(&Vt[par][tid * 16], vSrc);
    kSrc += 64 * HD;   // next 64-key tile of K rows
    vSrc += 64;        // next 64-key column-tile of V^T rows
  };
  auto qkt_sm_stage = [&](int par) {
    const char* klp = &Kl[par][0] + p * 128;
    bf16x8 kf[4][2];
#pragma unroll
    for (int nf = 0; nf < 4; ++nf)
#pragma unroll
      for (int ks = 0; ks < 2; ++ks)
        kf[nf][ks] = *(const bf16x8*)(klp + nf * 2048 + sCol[ks]);
    f32x4 s[4];
#pragma unroll
    for (int nf = 0; nf < 4; ++nf) s[nf] = (f32x4){0.f, 0.f, 0.f, 0.f};
    __builtin_amdgcn_s_setprio(1);
#pragma unroll
    for (int nf = 0; nf < 4; ++nf)
#pragma unroll
      for (int ks = 0; ks < 2; ++ks)
        s[nf] = __builtin_amdgcn_mfma_f32_16x16x32_bf16(kf[nf][ks], qf[ks], s[nf], 0, 0, 0);
    __builtin_amdgcn_s_setprio(0);
#pragma unroll
    for (int nf = 0; nf < 4; ++nf)
#pragma unroll
      for (int j = 0; j < 4; ++j)
        s[nf][j] = exp2f(s[nf][j]);
    char* plp = &Pl[0] + w * 2048 + p * 128;
#pragma unroll
    for (int nf = 0; nf < 4; ++nf) {
      uint2 val;
      val.x = cvtpk(s[nf][0], s[nf][1]);
      val.y = cvtpk(s[nf][2], s[nf][3]);
      *(uint2*)(plp + pwCol[nf]) = val;
    }
  };
  auto pv = [&](int par) {
    const char* plp = &Pl[0] + w * 2048 + p * 128;
    bf16x8 pf[2];
#pragma unroll
    for (int ks = 0; ks < 2; ++ks)
      pf[ks] = *(const bf16x8*)(plp + sCol[ks]);
    const char* vtp = &Vt[par][0] + p * 128;
    bf16x8 vb[4][2];
#pragma unroll
    for (int nfd = 0; nfd < 4; ++nfd)
#pragma unroll
      for (int ks = 0; ks < 2; ++ks)
        vb[nfd][ks] = *(const bf16x8*)(vtp + nfd * 2048 + sCol[ks]);
    __builtin_amdgcn_s_setprio(1);
#pragma unroll
    for (int nfd = 0; nfd < 4; ++nfd)
#pragma unroll
      for (int ks = 0; ks < 2; ++ks)
        o2[nfd] = __builtin_amdgcn_mfma_f32_16x16x32_bf16(vb[nfd][ks], pf[ks], o2[nfd], 0, 0, 0);
#pragma unroll
    for (int ks = 0; ks < 2; ++ks)
      ol = __builtin_amdgcn_mfma_f32_16x16x32_bf16(ones8, pf[ks], ol, 0, 0, 0);
    __builtin_amdgcn_s_setprio(0);
  };

  // prologue: stage tile 0
  gldKV(0);
  __syncthreads();   // barrier drains vmcnt: buf0 resident

  for (int it = 0; it < 16; ++it) {
    // tile 2it (par 0); prefetch 2it+1 (always exists, 2it+1 <= 31)
    gldKV(1);
    qkt_sm_stage(0);
    pv(0);
    __syncthreads();   // buf1 resident; all waves done with buf0
    // tile 2it+1 (par 1); prefetch 2it+2 if it < 15
    if (it < 15) gldKV(0);
    qkt_sm_stage(1);
    pv(1);
    __syncthreads();
  }

  // epilogue: out = 0.6*O/l + 0.4*(L@V); l broadcast from (g==0) lanes
  const float e1 = 4.3936934e-2f, e2 = 3.7266532e-6f, e3 = 6.1019804e-13f;
  const float lwv[4] = {1.f, e1, e2, e3};
  {
    const int q = qwv + p;
    const float lq = __shfl(ol[0], p);   // lane (g=0, p) holds row-0 sum for q
    const float inv = 0.6f / lq;
    float wsum = 0.f;
#pragma unroll
    for (int dd = -3; dd <= 3; ++dd) {
      const int kk = q + dd;
      if (kk >= 0 && kk < SEQ) wsum += lwv[dd < 0 ? -dd : dd];
    }
    const float wn = 0.4f / (wsum + 1e-10f);
#pragma unroll
    for (int nfd = 0; nfd < 4; ++nfd) {
      const int d0 = nfd * 16 + g * 4;
      float loc[4] = {0.f, 0.f, 0.f, 0.f};
#pragma unroll
      for (int dd = -3; dd <= 3; ++dd) {
        const int kk = q + dd;
        if (kk >= 0 && kk < SEQ) {
          const uint2 lv = *(const uint2*)&Vp[(size_t)kk * HD + d0];
          const float wt = lwv[dd < 0 ? -dd : dd];
          loc[0] = fmaf(wt, b2f((unsigned short)lv.x), loc[0]);
          loc[1] = fmaf(wt, b2f((unsigned short)(lv.x >> 16)), loc[1]);
          loc[2] = fmaf(wt, b2f((unsigned short)lv.y), loc[2]);
          loc[3] = fmaf(wt, b2f((unsigned short)(lv.y >> 16)), loc[3]);
        }
      }
      uint2 st;
      st.x = cvtpk(o2[nfd][0] * inv + loc[0] * wn, o2[nfd][1] * inv + loc[1] * wn);
      st.y = cvtpk(o2[nfd][2] * inv + loc[2] * wn, o2[nfd][3] * inv + loc[3] * wn);
      *(uint2*)&Y[((size_t)(b * SEQ + q)) * DIMC + h * HD + d0] = st;
    }
  }
}

extern "C" void kernel_launch(void* const* d_in, const int* in_sizes, int n_in,
                              void* d_out, int out_size, void* d_ws, size_t ws_size,
                              hipStream_t stream) {
  (void)in_sizes; (void)n_in; (void)out_size; (void)ws_size;
  const float* x  = (const float*)d_in[0];
  const float* Wq = (const float*)d_in[1];
  const float* bq = (const float*)d_in[2];
  const float* Wk = (const float*)d_in[3];
  const float* bk = (const float*)d_in[4];
  const float* Wv = (const float*)d_in[5];
  const float* bv = (const float*)d_in[6];
  const float* Wo = (const float*)d_in[7];
  const float* bo = (const float*)d_in[8];

  char* ws = (char*)d_ws;
  unsigned short* xb  = (unsigned short*)(ws);               // 8 MB
  unsigned short* Wqb = (unsigned short*)(ws + 8388608);     // 2 MB each, contiguous
  unsigned short* Wob = (unsigned short*)(ws + 14680064);
  unsigned short* Qh  = (unsigned short*)(ws + 16777216);    // 8 MB each (Q,K,V)
  unsigned short* Kh  = (unsigned short*)(ws + 25165824);
  unsigned short* Vh  = (unsigned short*)(ws + 33554432);
  unsigned short* Yb  = (unsigned short*)(ws + 41943040);    // 8 MB
  unsigned short* Vtg = (unsigned short*)(ws + 50331648);    // 8 MB transposed V

  dim3 blk(256);
  cvt_all<<<4096, blk, 0, stream>>>(x, Wq, Wk, Wv, Wo, xb, Wqb);

  gemm_qkv<<<dim3(32, 8, 3), blk, 0, stream>>>(xb, Wqb, bq, bk, bv, Qh, Vtg);

  attn_fused<<<dim3(32, 16), dim3(512), 0, stream>>>(Qh, Kh, Vtg, Vh, Yb);

  gemm_out<<<dim3(32, 16), blk, 0, stream>>>(Yb, Wob, bo, (float*)d_out);
}

// Round 19
// 129.050 us; speedup vs baseline: 1.0116x; 1.0116x over previous
//
#include <hip/hip_runtime.h>
#include <math.h>

typedef __bf16 bf16x8 __attribute__((ext_vector_type(8)));
typedef float f32x4 __attribute__((ext_vector_type(4)));

namespace {
constexpr int DIMC = 1024, NH = 16, HD = 64, SEQ = 2048;
constexpr float SCL2 = 0.1803368801f;  // 1/(tau*sqrt(64)) * log2(e), folded into Q
}

__device__ __forceinline__ unsigned short f2b(float f) {
  unsigned u = __float_as_uint(f);
  return (unsigned short)((u + 0x7fffu + ((u >> 16) & 1u)) >> 16);
}
__device__ __forceinline__ float b2f(unsigned short s) {
  return __uint_as_float((unsigned)s << 16);
}
__device__ __forceinline__ unsigned cvtpk(float lo, float hi) {
  unsigned r;
  asm("v_cvt_pk_bf16_f32 %0, %1, %2" : "=v"(r) : "v"(lo), "v"(hi));
  return r;
}
__device__ __forceinline__ void gld16(void* l, const void* g) {
  __builtin_amdgcn_global_load_lds(
      (const __attribute__((address_space(1))) void*)g,
      (__attribute__((address_space(3))) void*)l, 16, 0, 0);
}

// single fused fp32->bf16 pass: blocks [0,2048) convert x, [2048,4096) weights
__global__ __launch_bounds__(256)
void cvt_all(const float* __restrict__ x,
             const float* __restrict__ w0, const float* __restrict__ w1,
             const float* __restrict__ w2, const float* __restrict__ w3,
             unsigned short* __restrict__ xb, unsigned short* __restrict__ wb) {
  const int bid = blockIdx.x;
  const float* src;
  unsigned short* dst;
  int i;
  if (bid < 2048) {
    src = x; dst = xb; i = bid * 256 + threadIdx.x;
  } else {
    const int r = (bid - 2048) >> 9, lb = (bid - 2048) & 511;
    src = r == 0 ? w0 : r == 1 ? w1 : r == 2 ? w2 : w3;
    dst = wb + (size_t)r * 1048576;
    i = lb * 256 + threadIdx.x;
  }
  const float4* in4 = (const float4*)src;
  float4 a = in4[2 * i], b = in4[2 * i + 1];
  union { unsigned short u[8]; uint4 v; } r;
  r.u[0] = f2b(a.x); r.u[1] = f2b(a.y); r.u[2] = f2b(a.z); r.u[3] = f2b(a.w);
  r.u[4] = f2b(b.x); r.u[5] = f2b(b.y); r.u[6] = f2b(b.z); r.u[7] = f2b(b.w);
  ((uint4*)dst)[i] = r.v;
}

// ---- m97-structure GEMM tile: BM=BN=128, BK=32, gld16 staging, 16 MFMA/K-step ----
// kswz: K rows written with d ^= ((seq&7)<<3) (attention staging swizzle).
template<int MODE>
__device__ __forceinline__
void gemm_tile128(const unsigned short* __restrict__ A, const unsigned short* __restrict__ W,
                  const float* __restrict__ bias, void* __restrict__ Cout,
                  int bm, int bn, float scl, bool kswz, char* As, char* Bs) {
  const int tid = threadIdx.x, lane = tid & 63, w = tid >> 6;
  const int p = lane & 15, g = lane >> 4;
  const int wr = w >> 1, wc = w & 1;
  const int sr = tid >> 2, sc = (tid & 3) * 8;

  f32x4 acc[4][4];
#pragma unroll
  for (int mf = 0; mf < 4; ++mf)
#pragma unroll
    for (int nf = 0; nf < 4; ++nf)
      acc[mf][nf] = (f32x4){0.f, 0.f, 0.f, 0.f};

  const size_t arow0 = (size_t)(bm + sr) * DIMC + sc;
  const size_t arow1 = (size_t)(bm + 64 + sr) * DIMC + sc;
  const size_t brow0 = (size_t)(bn + sr) * DIMC + sc;
  const size_t brow1 = (size_t)(bn + 64 + sr) * DIMC + sc;

  for (int k0 = 0; k0 < DIMC; k0 += 32) {
    __syncthreads();
    gld16(&As[tid * 16],        &A[arow0 + k0]);
    gld16(&As[4096 + tid * 16], &A[arow1 + k0]);
    gld16(&Bs[tid * 16],        &W[brow0 + k0]);
    gld16(&Bs[4096 + tid * 16], &W[brow1 + k0]);
    __syncthreads();
    bf16x8 af[4], bfr[4];
#pragma unroll
    for (int mf = 0; mf < 4; ++mf)
      af[mf] = *(const bf16x8*)&As[(wr * 64 + mf * 16 + p) * 64 + g * 16];
#pragma unroll
    for (int nf = 0; nf < 4; ++nf)
      bfr[nf] = *(const bf16x8*)&Bs[(wc * 64 + nf * 16 + p) * 64 + g * 16];
#pragma unroll
    for (int mf = 0; mf < 4; ++mf)
#pragma unroll
      for (int nf = 0; nf < 4; ++nf)
        acc[mf][nf] = __builtin_amdgcn_mfma_f32_16x16x32_bf16(af[mf], bfr[nf], acc[mf][nf], 0, 0, 0);
  }

#pragma unroll
  for (int nf = 0; nf < 4; ++nf) {
    const int cg = bn + wc * 64 + nf * 16 + p;
    const float bv = bias[cg & (DIMC - 1)];
#pragma unroll
    for (int mf = 0; mf < 4; ++mf) {
#pragma unroll
      for (int j = 0; j < 4; ++j) {
        const int rg = bm + wr * 64 + mf * 16 + g * 4 + j;
        const float v = (acc[mf][nf][j] + bv) * scl;
        if (MODE == 0) {
          ((float*)Cout)[(size_t)rg * DIMC + cg] = v;
        } else {
          const int bb = rg >> 11, ss = rg & (SEQ - 1);
          const int hh = cg >> 6;
          int dd = cg & (HD - 1);
          if (kswz) dd ^= (ss & 7) << 3;
          ((unsigned short*)Cout)[(((size_t)(bb * NH + hh) * SEQ + ss) * HD) + dd] = f2b(v);
        }
      }
    }
  }
}

// fused Q/K/V projection: grid (32, 8, 3); z selects weight/bias/out.
// Q pre-scaled by SCL2; K written row-swizzled for the attention staging.
__global__ __launch_bounds__(256, 2)
void gemm_qkv(const unsigned short* __restrict__ A, const unsigned short* __restrict__ Wall,
              const float* __restrict__ bq, const float* __restrict__ bk,
              const float* __restrict__ bv, unsigned short* __restrict__ Out) {
  __shared__ char As[8192];
  __shared__ char Bs[8192];
  const int which = blockIdx.z;
  const unsigned short* W = Wall + (size_t)which * 1048576;
  const float* bias = which == 0 ? bq : which == 1 ? bk : bv;
  unsigned short* Cout = Out + (size_t)which * 4194304;
  const float scl = which == 0 ? SCL2 : 1.0f;
  gemm_tile128<1>(A, W, bias, Cout, blockIdx.x * 128, blockIdx.y * 128, scl, which == 1, As, Bs);
}

// ---- gemm_out: 128x64 tile, gld16 staging, 512 blocks = 2/CU ----
__global__ __launch_bounds__(256, 2)
void gemm_out(const unsigned short* __restrict__ A, const unsigned short* __restrict__ W,
              const float* __restrict__ bias, float* __restrict__ Cout) {
  __shared__ char As[8192];  // [128][32] bf16
  __shared__ char Bs[4096];  // [64][32] bf16
  const int tid = threadIdx.x, lane = tid & 63, w = tid >> 6;
  const int p = lane & 15, g = lane >> 4;
  const int wr = w >> 1, wc = w & 1;
  const int bm = blockIdx.x * 128, bn = blockIdx.y * 64;
  const int sr = tid >> 2, sc = (tid & 3) * 8;

  f32x4 acc[4][2];
#pragma unroll
  for (int mf = 0; mf < 4; ++mf)
#pragma unroll
    for (int nf = 0; nf < 2; ++nf)
      acc[mf][nf] = (f32x4){0.f, 0.f, 0.f, 0.f};

  const size_t arow0 = (size_t)(bm + sr) * DIMC + sc;
  const size_t arow1 = (size_t)(bm + 64 + sr) * DIMC + sc;
  const size_t brow  = (size_t)(bn + sr) * DIMC + sc;

  for (int k0 = 0; k0 < DIMC; k0 += 32) {
    __syncthreads();
    gld16(&As[tid * 16],        &A[arow0 + k0]);
    gld16(&As[4096 + tid * 16], &A[arow1 + k0]);
    gld16(&Bs[tid * 16],        &W[brow + k0]);
    __syncthreads();
    bf16x8 af[4], bfr[2];
#pragma unroll
    for (int mf = 0; mf < 4; ++mf)
      af[mf] = *(const bf16x8*)&As[(wr * 64 + mf * 16 + p) * 64 + g * 16];
#pragma unroll
    for (int nf = 0; nf < 2; ++nf)
      bfr[nf] = *(const bf16x8*)&Bs[(wc * 32 + nf * 16 + p) * 64 + g * 16];
#pragma unroll
    for (int mf = 0; mf < 4; ++mf)
#pragma unroll
      for (int nf = 0; nf < 2; ++nf)
        acc[mf][nf] = __builtin_amdgcn_mfma_f32_16x16x32_bf16(af[mf], bfr[nf], acc[mf][nf], 0, 0, 0);
  }

#pragma unroll
  for (int nf = 0; nf < 2; ++nf) {
    const int cg = bn + wc * 32 + nf * 16 + p;
    const float bv = bias[cg];
#pragma unroll
    for (int mf = 0; mf < 4; ++mf) {
#pragma unroll
      for (int j = 0; j < 4; ++j) {
        const int rg = bm + wr * 64 + mf * 16 + g * 4 + j;
        Cout[(size_t)rg * DIMC + cg] = acc[mf][nf][j] + bv;
      }
    }
  }
}

// Fused flash attention: shared gld16 K staging, reg-staged V, 8 waves x 16 q,
// P DOUBLE-BUFFERED so pv(t-1) overlaps qkt/softmax(t). One barrier/tile.
__global__ __launch_bounds__(512, 4)
void attn_fused(const unsigned short* __restrict__ Q, const unsigned short* __restrict__ K,
                const unsigned short* __restrict__ V, unsigned short* __restrict__ Y) {
  __shared__ char Kl[2][8192];   // K tile [64 key][64 d] bf16, pre-swizzled rows
  __shared__ char Vt[2][8192];   // V^T [64 d][64 key] bf16, XOR-swizzled
  __shared__ char Pl[2][16384];  // per-wave P [16 q][64 key] bf16, dbuf
  const int tid = threadIdx.x, lane = tid & 63, w = tid >> 6;
  const int p = lane & 15, g = lane >> 4;
  const int bh = blockIdx.x, b = bh >> 4, h = bh & 15;
  const int q0 = blockIdx.y * 128;
  const int qwv = q0 + w * 16;
  const size_t base = (size_t)bh * SEQ * HD;
  const unsigned short* Qp = Q + base;
  const unsigned short* Vp = V + base;

  union Vu { bf16x8 v; unsigned short u[8]; };

  // Q fragments: q = qwv + p, k(d) = ks*32 + g*8 + j
  bf16x8 qf[2];
#pragma unroll
  for (int ks = 0; ks < 2; ++ks)
    qf[ks] = *(const bf16x8*)&Qp[(size_t)(qwv + p) * HD + ks * 32 + g * 8];

  bf16x8 ones8;
  {
    union { unsigned short u[8]; bf16x8 v; } o;
#pragma unroll
    for (int e = 0; e < 8; ++e) o.u[e] = (p == 0) ? (unsigned short)0x3F80 : (unsigned short)0;
    ones8 = o.v;
  }

  // K staging: thread stages 16B of row tid>>3 (wave-uniform base + lane*16)
  const unsigned short* kSrc = K + base + (size_t)(tid >> 3) * HD + (tid & 7) * 8;
  // V staging: threads < 256 handle (key-pair kp, 8-d group vd0)
  const int kp = tid & 31, vd0 = ((tid >> 5) & 7) * 8;
  const bool vload = tid < 256;
  const unsigned short* vSrc = Vp + (size_t)(2 * kp) * HD + vd0;

  const int swz = (p & 7) << 4;
  int sCol[2], pwCol[4], colE[8];
#pragma unroll
  for (int ks = 0; ks < 2; ++ks) sCol[ks] = (ks * 64 + g * 16) ^ swz;
#pragma unroll
  for (int nf = 0; nf < 4; ++nf) pwCol[nf] = (nf * 32 + g * 8) ^ swz;
#pragma unroll
  for (int e = 0; e < 8; ++e) colE[e] = (kp * 4) ^ (e << 4);

  f32x4 o2[4];   // O^T frags: col q = p, row d = nfd*16 + g*4 + j
  f32x4 ol;      // l: row 0 (g==0,j==0), col q = p
#pragma unroll
  for (int nf = 0; nf < 4; ++nf) o2[nf] = (f32x4){0.f, 0.f, 0.f, 0.f};
  ol = (f32x4){0.f, 0.f, 0.f, 0.f};

  Vu v0A, v1A, v0B, v1B;

  auto gldK = [&](int par, int kb) {
    gld16(&Kl[par][tid * 16], kSrc + (size_t)kb * HD);
  };
  auto loadV = [&](Vu& a0, Vu& a1, int kb) {
    if (vload) {
      a0.v = *(const bf16x8*)(vSrc + (size_t)kb * HD);
      a1.v = *(const bf16x8*)(vSrc + (size_t)(kb + 1) * HD);
    }
  };
  auto writeV = [&](int par, Vu& a0, Vu& a1) {
    if (vload) {
      char* vtp = &Vt[par][0] + vd0 * 128;
#pragma unroll
      for (int e = 0; e < 8; ++e) {
        const unsigned val = (unsigned)a0.u[e] | ((unsigned)a1.u[e] << 16);
        *(unsigned*)(vtp + e * 128 + colE[e]) = val;
      }
    }
  };
  auto qkt_sm_stage = [&](int kpar, int ppar) {
    const char* klp = &Kl[kpar][0] + p * 128;
    bf16x8 kf[4][2];
#pragma unroll
    for (int nf = 0; nf < 4; ++nf)
#pragma unroll
      for (int ks = 0; ks < 2; ++ks)
        kf[nf][ks] = *(const bf16x8*)(klp + nf * 2048 + sCol[ks]);
    f32x4 s[4];
#pragma unroll
    for (int nf = 0; nf < 4; ++nf) s[nf] = (f32x4){0.f, 0.f, 0.f, 0.f};
    __builtin_amdgcn_s_setprio(1);
#pragma unroll
    for (int nf = 0; nf < 4; ++nf)
#pragma unroll
      for (int ks = 0; ks < 2; ++ks)
        s[nf] = __builtin_amdgcn_mfma_f32_16x16x32_bf16(kf[nf][ks], qf[ks], s[nf], 0, 0, 0);
    __builtin_amdgcn_s_setprio(0);
#pragma unroll
    for (int nf = 0; nf < 4; ++nf)
#pragma unroll
      for (int j = 0; j < 4; ++j)
        s[nf][j] = exp2f(s[nf][j]);
    char* plp = &Pl[ppar][0] + w * 2048 + p * 128;
#pragma unroll
    for (int nf = 0; nf < 4; ++nf) {
      uint2 val;
      val.x = cvtpk(s[nf][0], s[nf][1]);
      val.y = cvtpk(s[nf][2], s[nf][3]);
      *(uint2*)(plp + pwCol[nf]) = val;
    }
  };
  auto pv = [&](int vpar, int ppar) {
    const char* plp = &Pl[ppar][0] + w * 2048 + p * 128;
    bf16x8 pf[2];
#pragma unroll
    for (int ks = 0; ks < 2; ++ks)
      pf[ks] = *(const bf16x8*)(plp + sCol[ks]);
    const char* vtp = &Vt[vpar][0] + p * 128;
    bf16x8 vb[4][2];
#pragma unroll
    for (int nfd = 0; nfd < 4; ++nfd)
#pragma unroll
      for (int ks = 0; ks < 2; ++ks)
        vb[nfd][ks] = *(const bf16x8*)(vtp + nfd * 2048 + sCol[ks]);
    __builtin_amdgcn_s_setprio(1);
#pragma unroll
    for (int nfd = 0; nfd < 4; ++nfd)
#pragma unroll
      for (int ks = 0; ks < 2; ++ks)
        o2[nfd] = __builtin_amdgcn_mfma_f32_16x16x32_bf16(vb[nfd][ks], pf[ks], o2[nfd], 0, 0, 0);
#pragma unroll
    for (int ks = 0; ks < 2; ++ks)
      ol = __builtin_amdgcn_mfma_f32_16x16x32_bf16(ones8, pf[ks], ol, 0, 0, 0);
    __builtin_amdgcn_s_setprio(0);
  };

  // prologue: tile 0 (no pv yet)
  gldK(0, 0);
  loadV(v0A, v1A, 0);
  __syncthreads();                 // K(0) resident
  gldK(1, 64);
  loadV(v0B, v1B, 64);
  qkt_sm_stage(0, 0);              // P(0) -> Pl[0]
  writeV(0, v0A, v1A);             // V(0) -> Vt[0]
  __syncthreads();                 // K(1) resident; Vt[0] visible

  // main: tiles 1..30 in pairs; pv(t-1) overlaps qkt/softmax(t)
  for (int it = 0; it < 15; ++it) {
    const int t = 2 * it + 1;
    // t odd: kpar 1, ppar 1; pv(t-1): Vt[0], Pl[0]
    gldK(0, (t + 1) * 64);
    loadV(v0A, v1A, (t + 1) * 64);
    qkt_sm_stage(1, 1);
    pv(0, 0);
    writeV(1, v0B, v1B);
    __syncthreads();
    // t+1 even: kpar 0, ppar 0; pv(t): Vt[1], Pl[1]
    gldK(1, (t + 2) * 64);
    loadV(v0B, v1B, (t + 2) * 64);
    qkt_sm_stage(0, 0);
    pv(1, 1);
    writeV(0, v0A, v1A);
    __syncthreads();
  }
  // t = 31 (kpar 1, ppar 1), no prefetch
  qkt_sm_stage(1, 1);
  pv(0, 0);                        // tile 30
  writeV(1, v0B, v1B);
  __syncthreads();
  pv(1, 1);                        // tile 31

  // epilogue: out = 0.6*O/l + 0.4*(L@V); l broadcast from (g==0) lanes
  const float e1 = 4.3936934e-2f, e2 = 3.7266532e-6f, e3 = 6.1019804e-13f;
  const float lwv[4] = {1.f, e1, e2, e3};
  {
    const int q = qwv + p;
    const float lq = __shfl(ol[0], p);   // lane (g=0, p) holds row-0 sum for q
    const float inv = 0.6f / lq;
    float wsum = 0.f;
#pragma unroll
    for (int dd = -3; dd <= 3; ++dd) {
      const int kk = q + dd;
      if (kk >= 0 && kk < SEQ) wsum += lwv[dd < 0 ? -dd : dd];
    }
    const float wn = 0.4f / (wsum + 1e-10f);
#pragma unroll
    for (int nfd = 0; nfd < 4; ++nfd) {
      const int d0 = nfd * 16 + g * 4;
      float loc[4] = {0.f, 0.f, 0.f, 0.f};
#pragma unroll
      for (int dd = -3; dd <= 3; ++dd) {
        const int kk = q + dd;
        if (kk >= 0 && kk < SEQ) {
          const uint2 lv = *(const uint2*)&Vp[(size_t)kk * HD + d0];
          const float wt = lwv[dd < 0 ? -dd : dd];
          loc[0] = fmaf(wt, b2f((unsigned short)lv.x), loc[0]);
          loc[1] = fmaf(wt, b2f((unsigned short)(lv.x >> 16)), loc[1]);
          loc[2] = fmaf(wt, b2f((unsigned short)lv.y), loc[2]);
          loc[3] = fmaf(wt, b2f((unsigned short)(lv.y >> 16)), loc[3]);
        }
      }
      uint2 st;
      st.x = cvtpk(o2[nfd][0] * inv + loc[0] * wn, o2[nfd][1] * inv + loc[1] * wn);
      st.y = cvtpk(o2[nfd][2] * inv + loc[2] * wn, o2[nfd][3] * inv + loc[3] * wn);
      *(uint2*)&Y[((size_t)(b * SEQ + q)) * DIMC + h * HD + d0] = st;
    }
  }
}

extern "C" void kernel_launch(void* const* d_in, const int* in_sizes, int n_in,
                              void* d_out, int out_size, void* d_ws, size_t ws_size,
                              hipStream_t stream) {
  (void)in_sizes; (void)n_in; (void)out_size; (void)ws_size;
  const float* x  = (const float*)d_in[0];
  const float* Wq = (const float*)d_in[1];
  const float* bq = (const float*)d_in[2];
  const float* Wk = (const float*)d_in[3];
  const float* bk = (const float*)d_in[4];
  const float* Wv = (const float*)d_in[5];
  const float* bv = (const float*)d_in[6];
  const float* Wo = (const float*)d_in[7];
  const float* bo = (const float*)d_in[8];

  char* ws = (char*)d_ws;
  unsigned short* xb  = (unsigned short*)(ws);               // 8 MB
  unsigned short* Wqb = (unsigned short*)(ws + 8388608);     // 2 MB each, contiguous
  unsigned short* Wob = (unsigned short*)(ws + 14680064);
  unsigned short* Qh  = (unsigned short*)(ws + 16777216);    // 8 MB each (Q,K,V)
  unsigned short* Kh  = (unsigned short*)(ws + 25165824);
  unsigned short* Vh  = (unsigned short*)(ws + 33554432);
  unsigned short* Yb  = (unsigned short*)(ws + 41943040);    // 8 MB

  dim3 blk(256);
  cvt_all<<<4096, blk, 0, stream>>>(x, Wq, Wk, Wv, Wo, xb, Wqb);

  gemm_qkv<<<dim3(32, 8, 3), blk, 0, stream>>>(xb, Wqb, bq, bk, bv, Qh);

  attn_fused<<<dim3(32, 16), dim3(512), 0, stream>>>(Qh, Kh, Vh, Yb);

  gemm_out<<<dim3(32, 16), blk, 0, stream>>>(Yb, Wob, bo, (float*)d_out);
}

// Round 20
// 126.965 us; speedup vs baseline: 1.0282x; 1.0164x over previous
//
#include <hip/hip_runtime.h>
#include <math.h>

typedef __bf16 bf16x8 __attribute__((ext_vector_type(8)));
typedef float f32x4 __attribute__((ext_vector_type(4)));

namespace {
constexpr int DIMC = 1024, NH = 16, HD = 64, SEQ = 2048;
constexpr float SCL2 = 0.1803368801f;  // 1/(tau*sqrt(64)) * log2(e), folded into Q
}

__device__ __forceinline__ unsigned short f2b(float f) {
  unsigned u = __float_as_uint(f);
  return (unsigned short)((u + 0x7fffu + ((u >> 16) & 1u)) >> 16);
}
__device__ __forceinline__ float b2f(unsigned short s) {
  return __uint_as_float((unsigned)s << 16);
}
__device__ __forceinline__ unsigned cvtpk(float lo, float hi) {
  unsigned r;
  asm("v_cvt_pk_bf16_f32 %0, %1, %2" : "=v"(r) : "v"(lo), "v"(hi));
  return r;
}
__device__ __forceinline__ void gld16(void* l, const void* g) {
  __builtin_amdgcn_global_load_lds(
      (const __attribute__((address_space(1))) void*)g,
      (__attribute__((address_space(3))) void*)l, 16, 0, 0);
}

// counted-vmcnt barrier: allow the newest 3 VMEM ops (1 K-gld16 + 2 V loads)
// to stay in flight across the barrier; drain LDS (cross-wave Vt/P visibility).
#define TBAR() do {                                                        \
  asm volatile("s_waitcnt vmcnt(3) lgkmcnt(0)\n\ts_barrier" ::: "memory"); \
  __builtin_amdgcn_sched_barrier(0);                                       \
} while (0)

// single fused fp32->bf16 pass: blocks [0,2048) convert x, [2048,4096) weights
__global__ __launch_bounds__(256)
void cvt_all(const float* __restrict__ x,
             const float* __restrict__ w0, const float* __restrict__ w1,
             const float* __restrict__ w2, const float* __restrict__ w3,
             unsigned short* __restrict__ xb, unsigned short* __restrict__ wb) {
  const int bid = blockIdx.x;
  const float* src;
  unsigned short* dst;
  int i;
  if (bid < 2048) {
    src = x; dst = xb; i = bid * 256 + threadIdx.x;
  } else {
    const int r = (bid - 2048) >> 9, lb = (bid - 2048) & 511;
    src = r == 0 ? w0 : r == 1 ? w1 : r == 2 ? w2 : w3;
    dst = wb + (size_t)r * 1048576;
    i = lb * 256 + threadIdx.x;
  }
  const float4* in4 = (const float4*)src;
  float4 a = in4[2 * i], b = in4[2 * i + 1];
  union { unsigned short u[8]; uint4 v; } r;
  r.u[0] = f2b(a.x); r.u[1] = f2b(a.y); r.u[2] = f2b(a.z); r.u[3] = f2b(a.w);
  r.u[4] = f2b(b.x); r.u[5] = f2b(b.y); r.u[6] = f2b(b.z); r.u[7] = f2b(b.w);
  ((uint4*)dst)[i] = r.v;
}

// ---- m97-structure GEMM tile: BM=BN=128, BK=32, gld16 staging, 16 MFMA/K-step ----
// kswz: K rows written with d ^= ((seq&7)<<3) (attention staging swizzle).
template<int MODE>
__device__ __forceinline__
void gemm_tile128(const unsigned short* __restrict__ A, const unsigned short* __restrict__ W,
                  const float* __restrict__ bias, void* __restrict__ Cout,
                  int bm, int bn, float scl, bool kswz, char* As, char* Bs) {
  const int tid = threadIdx.x, lane = tid & 63, w = tid >> 6;
  const int p = lane & 15, g = lane >> 4;
  const int wr = w >> 1, wc = w & 1;
  const int sr = tid >> 2, sc = (tid & 3) * 8;

  f32x4 acc[4][4];
#pragma unroll
  for (int mf = 0; mf < 4; ++mf)
#pragma unroll
    for (int nf = 0; nf < 4; ++nf)
      acc[mf][nf] = (f32x4){0.f, 0.f, 0.f, 0.f};

  const size_t arow0 = (size_t)(bm + sr) * DIMC + sc;
  const size_t arow1 = (size_t)(bm + 64 + sr) * DIMC + sc;
  const size_t brow0 = (size_t)(bn + sr) * DIMC + sc;
  const size_t brow1 = (size_t)(bn + 64 + sr) * DIMC + sc;

  for (int k0 = 0; k0 < DIMC; k0 += 32) {
    __syncthreads();
    gld16(&As[tid * 16],        &A[arow0 + k0]);
    gld16(&As[4096 + tid * 16], &A[arow1 + k0]);
    gld16(&Bs[tid * 16],        &W[brow0 + k0]);
    gld16(&Bs[4096 + tid * 16], &W[brow1 + k0]);
    __syncthreads();
    bf16x8 af[4], bfr[4];
#pragma unroll
    for (int mf = 0; mf < 4; ++mf)
      af[mf] = *(const bf16x8*)&As[(wr * 64 + mf * 16 + p) * 64 + g * 16];
#pragma unroll
    for (int nf = 0; nf < 4; ++nf)
      bfr[nf] = *(const bf16x8*)&Bs[(wc * 64 + nf * 16 + p) * 64 + g * 16];
#pragma unroll
    for (int mf = 0; mf < 4; ++mf)
#pragma unroll
      for (int nf = 0; nf < 4; ++nf)
        acc[mf][nf] = __builtin_amdgcn_mfma_f32_16x16x32_bf16(af[mf], bfr[nf], acc[mf][nf], 0, 0, 0);
  }

#pragma unroll
  for (int nf = 0; nf < 4; ++nf) {
    const int cg = bn + wc * 64 + nf * 16 + p;
    const float bv = bias[cg & (DIMC - 1)];
#pragma unroll
    for (int mf = 0; mf < 4; ++mf) {
#pragma unroll
      for (int j = 0; j < 4; ++j) {
        const int rg = bm + wr * 64 + mf * 16 + g * 4 + j;
        const float v = (acc[mf][nf][j] + bv) * scl;
        if (MODE == 0) {
          ((float*)Cout)[(size_t)rg * DIMC + cg] = v;
        } else {
          const int bb = rg >> 11, ss = rg & (SEQ - 1);
          const int hh = cg >> 6;
          int dd = cg & (HD - 1);
          if (kswz) dd ^= (ss & 7) << 3;
          ((unsigned short*)Cout)[(((size_t)(bb * NH + hh) * SEQ + ss) * HD) + dd] = f2b(v);
        }
      }
    }
  }
}

// fused Q/K/V projection: grid (32, 8, 3); z selects weight/bias/out.
__global__ __launch_bounds__(256, 2)
void gemm_qkv(const unsigned short* __restrict__ A, const unsigned short* __restrict__ Wall,
              const float* __restrict__ bq, const float* __restrict__ bk,
              const float* __restrict__ bv, unsigned short* __restrict__ Out) {
  __shared__ char As[8192];
  __shared__ char Bs[8192];
  const int which = blockIdx.z;
  const unsigned short* W = Wall + (size_t)which * 1048576;
  const float* bias = which == 0 ? bq : which == 1 ? bk : bv;
  unsigned short* Cout = Out + (size_t)which * 4194304;
  const float scl = which == 0 ? SCL2 : 1.0f;
  gemm_tile128<1>(A, W, bias, Cout, blockIdx.x * 128, blockIdx.y * 128, scl, which == 1, As, Bs);
}

// ---- gemm_out: 128x64 tile, gld16 staging, 512 blocks = 2/CU ----
__global__ __launch_bounds__(256, 2)
void gemm_out(const unsigned short* __restrict__ A, const unsigned short* __restrict__ W,
              const float* __restrict__ bias, float* __restrict__ Cout) {
  __shared__ char As[8192];  // [128][32] bf16
  __shared__ char Bs[4096];  // [64][32] bf16
  const int tid = threadIdx.x, lane = tid & 63, w = tid >> 6;
  const int p = lane & 15, g = lane >> 4;
  const int wr = w >> 1, wc = w & 1;
  const int bm = blockIdx.x * 128, bn = blockIdx.y * 64;
  const int sr = tid >> 2, sc = (tid & 3) * 8;

  f32x4 acc[4][2];
#pragma unroll
  for (int mf = 0; mf < 4; ++mf)
#pragma unroll
    for (int nf = 0; nf < 2; ++nf)
      acc[mf][nf] = (f32x4){0.f, 0.f, 0.f, 0.f};

  const size_t arow0 = (size_t)(bm + sr) * DIMC + sc;
  const size_t arow1 = (size_t)(bm + 64 + sr) * DIMC + sc;
  const size_t brow  = (size_t)(bn + sr) * DIMC + sc;

  for (int k0 = 0; k0 < DIMC; k0 += 32) {
    __syncthreads();
    gld16(&As[tid * 16],        &A[arow0 + k0]);
    gld16(&As[4096 + tid * 16], &A[arow1 + k0]);
    gld16(&Bs[tid * 16],        &W[brow + k0]);
    __syncthreads();
    bf16x8 af[4], bfr[2];
#pragma unroll
    for (int mf = 0; mf < 4; ++mf)
      af[mf] = *(const bf16x8*)&As[(wr * 64 + mf * 16 + p) * 64 + g * 16];
#pragma unroll
    for (int nf = 0; nf < 2; ++nf)
      bfr[nf] = *(const bf16x8*)&Bs[(wc * 32 + nf * 16 + p) * 64 + g * 16];
#pragma unroll
    for (int mf = 0; mf < 4; ++mf)
#pragma unroll
      for (int nf = 0; nf < 2; ++nf)
        acc[mf][nf] = __builtin_amdgcn_mfma_f32_16x16x32_bf16(af[mf], bfr[nf], acc[mf][nf], 0, 0, 0);
  }

#pragma unroll
  for (int nf = 0; nf < 2; ++nf) {
    const int cg = bn + wc * 32 + nf * 16 + p;
    const float bv = bias[cg];
#pragma unroll
    for (int mf = 0; mf < 4; ++mf) {
#pragma unroll
      for (int j = 0; j < 4; ++j) {
        const int rg = bm + wr * 64 + mf * 16 + g * 4 + j;
        Cout[(size_t)rg * DIMC + cg] = acc[mf][nf][j] + bv;
      }
    }
  }
}

// Fused flash attention: K TRIPLE-buffered gld16 prefetch (depth 2), V reg-dbuf,
// P single-buffered per wave; counted-vmcnt barrier (no full drain in main loop).
__global__ __launch_bounds__(512, 4)
void attn_fused(const unsigned short* __restrict__ Q, const unsigned short* __restrict__ K,
                const unsigned short* __restrict__ V, unsigned short* __restrict__ Y) {
  __shared__ char Kl[3][8192];   // K tile [64 key][64 d] bf16, pre-swizzled rows
  __shared__ char Vt[2][8192];   // V^T [64 d][64 key] bf16, XOR-swizzled
  __shared__ char Pl[16384];     // per-wave P [16 q][64 key] bf16 (8 x 2KB)
  const int tid = threadIdx.x, lane = tid & 63, w = tid >> 6;
  const int p = lane & 15, g = lane >> 4;
  const int bh = blockIdx.x, b = bh >> 4, h = bh & 15;
  const int q0 = blockIdx.y * 128;
  const int qwv = q0 + w * 16;
  const size_t base = (size_t)bh * SEQ * HD;
  const unsigned short* Qp = Q + base;
  const unsigned short* Vp = V + base;

  union Vu { bf16x8 v; unsigned short u[8]; };

  // Q fragments: q = qwv + p, k(d) = ks*32 + g*8 + j
  bf16x8 qf[2];
#pragma unroll
  for (int ks = 0; ks < 2; ++ks)
    qf[ks] = *(const bf16x8*)&Qp[(size_t)(qwv + p) * HD + ks * 32 + g * 8];

  bf16x8 ones8;
  {
    union { unsigned short u[8]; bf16x8 v; } o;
#pragma unroll
    for (int e = 0; e < 8; ++e) o.u[e] = (p == 0) ? (unsigned short)0x3F80 : (unsigned short)0;
    ones8 = o.v;
  }

  // K staging: thread stages 16B of row tid>>3 (wave-uniform base + lane*16)
  const unsigned short* kSrc = K + base + (size_t)(tid >> 3) * HD + (tid & 7) * 8;
  // V staging: threads < 256 handle (key-pair kp, 8-d group vd0)
  const int kp = tid & 31, vd0 = ((tid >> 5) & 7) * 8;
  const bool vload = tid < 256;
  const unsigned short* vSrc = Vp + (size_t)(2 * kp) * HD + vd0;

  const int swz = (p & 7) << 4;
  int sCol[2], pwCol[4], colE[8];
#pragma unroll
  for (int ks = 0; ks < 2; ++ks) sCol[ks] = (ks * 64 + g * 16) ^ swz;
#pragma unroll
  for (int nf = 0; nf < 4; ++nf) pwCol[nf] = (nf * 32 + g * 8) ^ swz;
#pragma unroll
  for (int e = 0; e < 8; ++e) colE[e] = (kp * 4) ^ (e << 4);

  f32x4 o2[4];   // O^T frags: col q = p, row d = nfd*16 + g*4 + j
  f32x4 ol;      // l: row 0 (g==0,j==0), col q = p
#pragma unroll
  for (int nf = 0; nf < 4; ++nf) o2[nf] = (f32x4){0.f, 0.f, 0.f, 0.f};
  ol = (f32x4){0.f, 0.f, 0.f, 0.f};

  Vu v0A, v1A, v0B, v1B;

  auto gldK = [&](int par, int kb) {
    gld16(&Kl[par][tid * 16], kSrc + (size_t)kb * HD);
  };
  auto loadV = [&](Vu& a0, Vu& a1, int kb) {
    if (vload) {
      a0.v = *(const bf16x8*)(vSrc + (size_t)kb * HD);
      a1.v = *(const bf16x8*)(vSrc + (size_t)(kb + 1) * HD);
    }
  };
  auto writeV = [&](int par, Vu& a0, Vu& a1) {
    if (vload) {
      char* vtp = &Vt[par][0] + vd0 * 128;
#pragma unroll
      for (int e = 0; e < 8; ++e) {
        const unsigned val = (unsigned)a0.u[e] | ((unsigned)a1.u[e] << 16);
        *(unsigned*)(vtp + e * 128 + colE[e]) = val;
      }
    }
  };
  auto qkt_sm_stage = [&](int kpar) {
    const char* klp = &Kl[kpar][0] + p * 128;
    bf16x8 kf[4][2];
#pragma unroll
    for (int nf = 0; nf < 4; ++nf)
#pragma unroll
      for (int ks = 0; ks < 2; ++ks)
        kf[nf][ks] = *(const bf16x8*)(klp + nf * 2048 + sCol[ks]);
    f32x4 s[4];
#pragma unroll
    for (int nf = 0; nf < 4; ++nf) s[nf] = (f32x4){0.f, 0.f, 0.f, 0.f};
    __builtin_amdgcn_s_setprio(1);
#pragma unroll
    for (int nf = 0; nf < 4; ++nf)
#pragma unroll
      for (int ks = 0; ks < 2; ++ks)
        s[nf] = __builtin_amdgcn_mfma_f32_16x16x32_bf16(kf[nf][ks], qf[ks], s[nf], 0, 0, 0);
    __builtin_amdgcn_s_setprio(0);
#pragma unroll
    for (int nf = 0; nf < 4; ++nf)
#pragma unroll
      for (int j = 0; j < 4; ++j)
        s[nf][j] = exp2f(s[nf][j]);
    char* plp = &Pl[0] + w * 2048 + p * 128;
#pragma unroll
    for (int nf = 0; nf < 4; ++nf) {
      uint2 val;
      val.x = cvtpk(s[nf][0], s[nf][1]);
      val.y = cvtpk(s[nf][2], s[nf][3]);
      *(uint2*)(plp + pwCol[nf]) = val;
    }
  };
  auto pv = [&](int vpar) {
    const char* plp = &Pl[0] + w * 2048 + p * 128;
    bf16x8 pf[2];
#pragma unroll
    for (int ks = 0; ks < 2; ++ks)
      pf[ks] = *(const bf16x8*)(plp + sCol[ks]);
    const char* vtp = &Vt[vpar][0] + p * 128;
    bf16x8 vb[4][2];
#pragma unroll
    for (int nfd = 0; nfd < 4; ++nfd)
#pragma unroll
      for (int ks = 0; ks < 2; ++ks)
        vb[nfd][ks] = *(const bf16x8*)(vtp + nfd * 2048 + sCol[ks]);
    __builtin_amdgcn_s_setprio(1);
#pragma unroll
    for (int nfd = 0; nfd < 4; ++nfd)
#pragma unroll
      for (int ks = 0; ks < 2; ++ks)
        o2[nfd] = __builtin_amdgcn_mfma_f32_16x16x32_bf16(vb[nfd][ks], pf[ks], o2[nfd], 0, 0, 0);
#pragma unroll
    for (int ks = 0; ks < 2; ++ks)
      ol = __builtin_amdgcn_mfma_f32_16x16x32_bf16(ones8, pf[ks], ol, 0, 0, 0);
    __builtin_amdgcn_s_setprio(0);
  };

  // prologue: K(0),K(1) staged; V(0) in regs; one full drain
  gldK(0, 0);
  gldK(1, 64);
  loadV(v0A, v1A, 0);
  __syncthreads();

  // main loop: 30 tiles in 5 rounds of 6 (kpar period 3 x vpar period 2).
  // per tile t: issue K(t+2), V(t+1) -> qkt/softmax/P(t) -> writeV(t) ->
  // counted barrier (newest 3 VMEM in flight) -> pv(t).
  for (int it = 0; it < 5; ++it) {
    const int t0 = it * 6;
    gldK(2, (t0 + 2) * 64); loadV(v0B, v1B, (t0 + 1) * 64);
    qkt_sm_stage(0); writeV(0, v0A, v1A); TBAR(); pv(0);

    gldK(0, (t0 + 3) * 64); loadV(v0A, v1A, (t0 + 2) * 64);
    qkt_sm_stage(1); writeV(1, v0B, v1B); TBAR(); pv(1);

    gldK(1, (t0 + 4) * 64); loadV(v0B, v1B, (t0 + 3) * 64);
    qkt_sm_stage(2); writeV(0, v0A, v1A); TBAR(); pv(0);

    gldK(2, (t0 + 5) * 64); loadV(v0A, v1A, (t0 + 4) * 64);
    qkt_sm_stage(0); writeV(1, v0B, v1B); TBAR(); pv(1);

    gldK(0, (t0 + 6) * 64); loadV(v0B, v1B, (t0 + 5) * 64);
    qkt_sm_stage(1); writeV(0, v0A, v1A); TBAR(); pv(0);

    gldK(1, (t0 + 7) * 64); loadV(v0A, v1A, (t0 + 6) * 64);
    qkt_sm_stage(2); writeV(1, v0B, v1B); TBAR(); pv(1);
  }
  // t = 30 (kpar 0, vpar 0, A): no K prefetch; V(31) -> B
  loadV(v0B, v1B, 31 * 64);
  qkt_sm_stage(0); writeV(0, v0A, v1A); TBAR(); pv(0);
  // t = 31 (kpar 1, vpar 1, B): no prefetch
  qkt_sm_stage(1); writeV(1, v0B, v1B); TBAR(); pv(1);

  // epilogue: out = 0.6*O/l + 0.4*(L@V); l broadcast from (g==0) lanes
  const float e1 = 4.3936934e-2f, e2 = 3.7266532e-6f, e3 = 6.1019804e-13f;
  const float lwv[4] = {1.f, e1, e2, e3};
  {
    const int q = qwv + p;
    const float lq = __shfl(ol[0], p);   // lane (g=0, p) holds row-0 sum for q
    const float inv = 0.6f / lq;
    float wsum = 0.f;
#pragma unroll
    for (int dd = -3; dd <= 3; ++dd) {
      const int kk = q + dd;
      if (kk >= 0 && kk < SEQ) wsum += lwv[dd < 0 ? -dd : dd];
    }
    const float wn = 0.4f / (wsum + 1e-10f);
#pragma unroll
    for (int nfd = 0; nfd < 4; ++nfd) {
      const int d0 = nfd * 16 + g * 4;
      float loc[4] = {0.f, 0.f, 0.f, 0.f};
#pragma unroll
      for (int dd = -3; dd <= 3; ++dd) {
        const int kk = q + dd;
        if (kk >= 0 && kk < SEQ) {
          const uint2 lv = *(const uint2*)&Vp[(size_t)kk * HD + d0];
          const float wt = lwv[dd < 0 ? -dd : dd];
          loc[0] = fmaf(wt, b2f((unsigned short)lv.x), loc[0]);
          loc[1] = fmaf(wt, b2f((unsigned short)(lv.x >> 16)), loc[1]);
          loc[2] = fmaf(wt, b2f((unsigned short)lv.y), loc[2]);
          loc[3] = fmaf(wt, b2f((unsigned short)(lv.y >> 16)), loc[3]);
        }
      }
      uint2 st;
      st.x = cvtpk(o2[nfd][0] * inv + loc[0] * wn, o2[nfd][1] * inv + loc[1] * wn);
      st.y = cvtpk(o2[nfd][2] * inv + loc[2] * wn, o2[nfd][3] * inv + loc[3] * wn);
      *(uint2*)&Y[((size_t)(b * SEQ + q)) * DIMC + h * HD + d0] = st;
    }
  }
}

extern "C" void kernel_launch(void* const* d_in, const int* in_sizes, int n_in,
                              void* d_out, int out_size, void* d_ws, size_t ws_size,
                              hipStream_t stream) {
  (void)in_sizes; (void)n_in; (void)out_size; (void)ws_size;
  const float* x  = (const float*)d_in[0];
  const float* Wq = (const float*)d_in[1];
  const float* bq = (const float*)d_in[2];
  const float* Wk = (const float*)d_in[3];
  const float* bk = (const float*)d_in[4];
  const float* Wv = (const float*)d_in[5];
  const float* bv = (const float*)d_in[6];
  const float* Wo = (const float*)d_in[7];
  const float* bo = (const float*)d_in[8];

  char* ws = (char*)d_ws;
  unsigned short* xb  = (unsigned short*)(ws);               // 8 MB
  unsigned short* Wqb = (unsigned short*)(ws + 8388608);     // 2 MB each, contiguous
  unsigned short* Wob = (unsigned short*)(ws + 14680064);
  unsigned short* Qh  = (unsigned short*)(ws + 16777216);    // 8 MB each (Q,K,V)
  unsigned short* Kh  = (unsigned short*)(ws + 25165824);
  unsigned short* Vh  = (unsigned short*)(ws + 33554432);
  unsigned short* Yb  = (unsigned short*)(ws + 41943040);    // 8 MB

  dim3 blk(256);
  cvt_all<<<4096, blk, 0, stream>>>(x, Wq, Wk, Wv, Wo, xb, Wqb);

  gemm_qkv<<<dim3(32, 8, 3), blk, 0, stream>>>(xb, Wqb, bq, bk, bv, Qh);

  attn_fused<<<dim3(32, 16), dim3(512), 0, stream>>>(Qh, Kh, Vh, Yb);

  gemm_out<<<dim3(32, 16), blk, 0, stream>>>(Yb, Wob, bo, (float*)d_out);
}